// Round 6
// baseline (469.600 us; speedup 1.0000x reference)
//
#include <hip/hip_runtime.h>
#include <hip/hip_bf16.h>

// ---------------------------------------------------------------------------
// Spiking Swin block: QKV(+LIF) -> binary attention (+rpb) -> PV -> proj(+LIF)
// I/O: float32. MFMA bf16 16x16x32 for GEMM work (exact for 0/1 spikes).
//
// *** R10 = MEASUREMENT PROBE #2 (pipeline + 2 extra k_attn launches) ***
//
// Measurement ledger:
//  R3: timed window has ~245us harness poison fills (fixed); ours ~110us.
//  R5: LDS-only barriers (no vmcnt drain): NULL.
//  R7: rpb 268MB read stream -> 6.3KB LDS gather: NULL (L3 had hidden it).
//  R8 PROBE (2x full pipeline): delta=91us = true warm pipeline cost.
//     Floor arithmetic: k_attn ~46 (285MB st), k_qkv ~7, k_proj ~9 => ~60us.
//     => ~31us unexplained: interior slack OR 3 launch boundaries.
//  R9: k_proj 2 blocks/CU + T14 prefetch, k_qkv T14 prefetch: NULL.
//     Four nulls total -> interior-slack theories falsified one by one.
//  R10 (this round): launch A,B,C,B,B. Extra B launches are idempotent
//     (rewrite attn/o_ws byte-identically; C's out0 untouched).
//     dur - 353.5 = 2 x warm-cost(k_attn).
//       ~449-458 -> k_attn AT floor -> slack is boundaries/qkv/proj
//                    -> fuse kernels or declare roofline with accounting.
//       >=472    -> k_attn interior fat -> rebuild k_attn schedule.
// ---------------------------------------------------------------------------

typedef __attribute__((ext_vector_type(8))) short bf16x8;   // 8 bf16 = 4 VGPRs
typedef __attribute__((ext_vector_type(4))) float f32x4;

#define MFMA16(a, b, c) __builtin_amdgcn_mfma_f32_16x16x32_bf16((a), (b), (c), 0, 0, 0)

// LDS-only barrier: wait own LDS ops, then rendezvous. Does NOT drain vmcnt,
// so in-flight global (nontemporal) stores / prefetch loads keep flying.
#define BAR_LDS()                                                \
    do {                                                         \
        asm volatile("s_waitcnt lgkmcnt(0)" ::: "memory");       \
        __builtin_amdgcn_s_barrier();                            \
    } while (0)

__device__ __forceinline__ unsigned short f2bf(float f) {
    union { __hip_bfloat16 h; unsigned short u; } cv;
    cv.h = __float2bfloat16(f);                      // RNE
    return cv.u;
}

// Convert 8 f32 (two float4 regs) -> 8 bf16, 16B store to LDS.
__device__ __forceinline__ void cvt8_store_reg(unsigned short* dst, float4 f0, float4 f1) {
    unsigned short h[8];
    h[0] = f2bf(f0.x); h[1] = f2bf(f0.y); h[2] = f2bf(f0.z); h[3] = f2bf(f0.w);
    h[4] = f2bf(f1.x); h[5] = f2bf(f1.y); h[6] = f2bf(f1.z); h[7] = f2bf(f1.w);
    *(uint4*)dst = *(const uint4*)h;
}

__device__ __forceinline__ void cvt8_store(unsigned short* dst, const float* src) {
    float4 f0 = *(const float4*)(src);
    float4 f1 = *(const float4*)(src + 4);
    cvt8_store_reg(dst, f0, f1);
}

// ---------------------------------------------------------------------------
// Kernel A: blockIdx.y in {0,1,2}: per-weight GEMM X@W^T (MFMA) + LIF over t,
// bit-packed spike output. x tile for t+1 register-prefetched (T14).
// ---------------------------------------------------------------------------
__global__ __launch_bounds__(256) void k_qkv_lif(
    const float* __restrict__ x,
    const float* __restrict__ Wq,
    const float* __restrict__ Wk,
    const float* __restrict__ Wv,
    unsigned int* __restrict__ qbits,
    unsigned int* __restrict__ kbits,
    unsigned int* __restrict__ vbits)
{
    __shared__ unsigned short Wl[128 * 136];   // W rows d (N) x cols c (K), pad +8
    __shared__ unsigned short Xl[64 * 136];    // X tile / spike tile (reused)

    const int tid = threadIdx.x;
    const int wv = tid >> 6, lane = tid & 63;
    const int l15 = lane & 15, lh = lane >> 4;
    const int wsel = blockIdx.y;
    const float* W = (wsel == 0) ? Wq : (wsel == 1) ? Wk : Wv;
    unsigned int* bits = (wsel == 0) ? qbits : (wsel == 1) ? kbits : vbits;
    const int B = blockIdx.x;

    {   // stage W (128x128 f32 -> bf16)
#pragma unroll
        for (int i = 0; i < 8; ++i) {
            int e = i * 2048 + tid * 8;
            cvt8_store(&Wl[(e >> 7) * 136 + (e & 127)], W + e);
        }
    }

    // prefetch x(t=0): 32 floats/thread in regs (e = r*128+cc flat)
    float4 px[8];
    {
        const float* xg = x + B * 8192;
#pragma unroll
        for (int i = 0; i < 4; ++i) {
            int e = i * 2048 + tid * 8;
            px[2 * i]     = *(const float4*)(xg + e);
            px[2 * i + 1] = *(const float4*)(xg + e + 4);
        }
    }

    f32x4 vst[8];                                   // LIF membrane, persists over t
#pragma unroll
    for (int nt = 0; nt < 8; ++nt) vst[nt] = (f32x4){0.f, 0.f, 0.f, 0.f};

    for (int t = 0; t < 4; ++t) {
        BAR_LDS();                                  // Xl free (pack reads done)
#pragma unroll
        for (int i = 0; i < 4; ++i) {               // regs -> bf16 -> Xl
            int e = i * 2048 + tid * 8;
            cvt8_store_reg(&Xl[(e >> 7) * 136 + (e & 127)], px[2 * i], px[2 * i + 1]);
        }
        BAR_LDS();

        if (t < 3) {                                // issue t+1 loads NOW;
            const float* xg = x + (t + 1) * 2097152 + B * 8192;  // fly under MFMA
#pragma unroll
            for (int i = 0; i < 4; ++i) {
                int e = i * 2048 + tid * 8;
                px[2 * i]     = *(const float4*)(xg + e);
                px[2 * i + 1] = *(const float4*)(xg + e + 4);
            }
        }

        f32x4 acc[8];
#pragma unroll
        for (int nt = 0; nt < 8; ++nt) acc[nt] = (f32x4){0.f, 0.f, 0.f, 0.f};
#pragma unroll
        for (int kk = 0; kk < 4; ++kk) {
            bf16x8 a = *(const bf16x8*)&Xl[(wv * 16 + l15) * 136 + kk * 32 + lh * 8];
#pragma unroll
            for (int nt = 0; nt < 8; ++nt) {
                bf16x8 b = *(const bf16x8*)&Wl[(nt * 16 + l15) * 136 + kk * 32 + lh * 8];
                acc[nt] = MFMA16(a, b, acc[nt]);
            }
        }
        // LIF: v += (y-v)/2; s=(v>=1); v*=(1-s); spike shorts -> Xl
        unsigned short sp[8][4];
#pragma unroll
        for (int nt = 0; nt < 8; ++nt) {
#pragma unroll
            for (int reg = 0; reg < 4; ++reg) {
                float y = acc[nt][reg];
                float v = vst[nt][reg];
                v = v + (y - v) * 0.5f;
                float s = (v >= 1.0f) ? 1.0f : 0.0f;
                vst[nt][reg] = v * (1.0f - s);
                sp[nt][reg] = (s != 0.0f) ? (unsigned short)1 : (unsigned short)0;
            }
        }
        BAR_LDS();                                  // all MFMA reads of Xl done
#pragma unroll
        for (int nt = 0; nt < 8; ++nt)
#pragma unroll
            for (int reg = 0; reg < 4; ++reg)
                Xl[(wv * 16 + lh * 4 + reg) * 136 + nt * 16 + l15] = sp[nt][reg];
        BAR_LDS();
        // pack: thread u owns n=u: row hw=u>>2, cols (u&3)*32 .. +31 -> 32 bits
        {
            const unsigned short* rowp = &Xl[(tid >> 2) * 136 + (tid & 3) * 32];
            unsigned int mask = 0;
#pragma unroll
            for (int j8 = 0; j8 < 4; ++j8) {
                uint4 u = *(const uint4*)(rowp + j8 * 8);
                int base = j8 * 8;
                if (u.x & 0xFFFFu) mask |= 1u << (base + 0);
                if (u.x >> 16)     mask |= 1u << (base + 1);
                if (u.y & 0xFFFFu) mask |= 1u << (base + 2);
                if (u.y >> 16)     mask |= 1u << (base + 3);
                if (u.z & 0xFFFFu) mask |= 1u << (base + 4);
                if (u.z >> 16)     mask |= 1u << (base + 5);
                if (u.w & 0xFFFFu) mask |= 1u << (base + 6);
                if (u.w >> 16)     mask |= 1u << (base + 7);
            }
            bits[(t * 256 + B) * 256 + tid] = mask;  // coalesced 1KB
        }
    }
}

// ---------------------------------------------------------------------------
// Kernel B: one block per group g=(b,head). attn[n][m] = popc(q&k)*SC + rpb,
// float4 nontemporal stores; bf16 copy in LDS; o = attn@v via MFMA.
// rpb gathered from 6.3 KB per-head LDS table (ri = base(n) - dm(m)).
// LDS 40.1 KB -> 4 blocks/CU.
// ---------------------------------------------------------------------------
__global__ __launch_bounds__(256) void k_attn(
    const unsigned int* __restrict__ qbits,
    const unsigned int* __restrict__ kbits,
    const unsigned int* __restrict__ vbits,
    const float* __restrict__ tbl,
    float* __restrict__ attn_out,
    unsigned short* __restrict__ o_ws)
{
    __shared__ unsigned short vT[32 * 264];    // v transposed: [d][m], pad +8
    __shared__ unsigned short attnL[32 * 264]; // attn chunk bf16: [n_loc][m]
    __shared__ float tblL[1575];               // per-head rpb base table (7*15*15)

    const int tid = threadIdx.x;
    const int wv = tid >> 6, lane = tid & 63;
    const int l15 = lane & 15, lh = lane >> 4;
    const int g = blockIdx.x, hh = g & 3;

    // stage per-head rpb table: tblL[ri] = tbl[ri*4 + hh]
    for (int i = tid; i < 1575; i += 256)
        tblL[i] = tbl[i * 4 + hh];

    uint4 km = *(const uint4*)&kbits[g * 256 + (tid & 63) * 4];
    {   // v bits -> bf16 vT[d][m]
        unsigned int vb = vbits[g * 256 + tid];
#pragma unroll
        for (int d = 0; d < 32; ++d)
            vT[d * 264 + tid] = ((vb >> d) & 1u) ? (unsigned short)0x3F80
                                                 : (unsigned short)0;
    }

    // per-lane dm for the 4 owned columns m = m0..m0+3:
    // dm = zm*225 + ym*15 + xm  (ri = base(n) - dm)
    const int m0 = (tid & 63) * 4;
    int dm[4];
#pragma unroll
    for (int i = 0; i < 4; ++i) {
        int m = m0 + i;
        dm[i] = (m >> 6) * 225 + ((m >> 3) & 7) * 15 + (m & 7);
    }

    BAR_LDS();                                 // vT + tblL ready

    const float SC = 0.17677669529663687f;     // 32^-0.5
    float* attn_b = attn_out + (size_t)g * 65536;
    unsigned short* ob = o_ws + g * 8192;
    const int rowb = __builtin_amdgcn_readfirstlane(wv * 8);  // wave row base
    const int rt = wv >> 1, nh = wv & 1;       // PV work split

    for (int c = 0; c < 8; ++c) {              // 32-row chunks
        // wave handles rows n = c*32 + rowb + j (contiguous 8-row band)
#pragma unroll
        for (int j = 0; j < 8; ++j) {
            int n = c * 32 + rowb + j;                       // wave-uniform
            unsigned int qn = qbits[g * 256 + n];            // s_load (uniform)
            int zn = n >> 6, yn = (n >> 3) & 7, xn = n & 7;
            int basei = zn * 225 + yn * 15 + xn + 787;       // scalar
            f32x4 av;
            av.x = (float)__popc(qn & km.x) * SC + tblL[basei - dm[0]];
            av.y = (float)__popc(qn & km.y) * SC + tblL[basei - dm[1]];
            av.z = (float)__popc(qn & km.z) * SC + tblL[basei - dm[2]];
            av.w = (float)__popc(qn & km.w) * SC + tblL[basei - dm[3]];
            __builtin_nontemporal_store(av, (f32x4*)(attn_b + n * 256 + m0));
            unsigned int p0 = (unsigned int)f2bf(av.x) | ((unsigned int)f2bf(av.y) << 16);
            unsigned int p1 = (unsigned int)f2bf(av.z) | ((unsigned int)f2bf(av.w) << 16);
            uint2 pk; pk.x = p0; pk.y = p1;
            *(uint2*)&attnL[(rowb + j) * 264 + m0] = pk;
        }
        BAR_LDS();
        // o(32x32) = attnL(32x256) @ v(256x32); wave (rt,nh) -> 16x16 tile
        f32x4 oc = (f32x4){0.f, 0.f, 0.f, 0.f};
#pragma unroll
        for (int kk = 0; kk < 8; ++kk) {
            bf16x8 a = *(const bf16x8*)&attnL[(rt * 16 + l15) * 264 + kk * 32 + lh * 8];
            bf16x8 b = *(const bf16x8*)&vT[(nh * 16 + l15) * 264 + kk * 32 + lh * 8];
            oc = MFMA16(a, b, oc);
        }
#pragma unroll
        for (int reg = 0; reg < 4; ++reg) {
            int n = c * 32 + rt * 16 + lh * 4 + reg;
            ob[n * 32 + nh * 16 + l15] = f2bf(oc[reg]);
        }
        BAR_LDS();                              // attnL reuse next chunk
    }
}

// ---------------------------------------------------------------------------
// Kernel C: gather o across heads -> A(256x128); Y = A@Wp^T + bias; LIF over
// t2. Grid 512 = (b, half); 2 blocks/CU, 8 waves; T14 chunk prefetch.
// ---------------------------------------------------------------------------
__global__ __launch_bounds__(256) void k_proj_lif(
    const unsigned short* __restrict__ o_ws,
    const float* __restrict__ Wp,
    const float* __restrict__ bp,
    float* __restrict__ out0)
{
    __shared__ unsigned short Wl[128 * 136];
    __shared__ unsigned short Al[64 * 136];

    const int tid = threadIdx.x;
    const int wv = tid >> 6, lane = tid & 63;
    const int l15 = lane & 15, lh = lane >> 4;
    const int b = blockIdx.x >> 1, half = blockIdx.x & 1;

    {   // stage Wproj (f32 -> bf16)
#pragma unroll
        for (int i = 0; i < 8; ++i) {
            int e = i * 2048 + tid * 8;
            cvt8_store(&Wl[(e >> 7) * 136 + (e & 127)], Wp + e);
        }
    }

    float biasf[2];
#pragma unroll
    for (int ntl = 0; ntl < 2; ++ntl)
        biasf[ntl] = bp[(wv * 2 + ntl) * 16 + l15];

    const unsigned short* ob = o_ws + b * 32768;   // o[b][head][n][hd] bf16

    // prefetch chunk c0 = half*2: Al rows lr2 = t2*16+rit, cols cc = head*32+hd
    uint4 pa[4];
    {
        int c = half * 2;
#pragma unroll
        for (int i = 0; i < 4; ++i) {
            int e = i * 2048 + tid * 8;
            int lr2 = e >> 7, cc = e & 127;
            int t2 = lr2 >> 4, rit = lr2 & 15;
            int n = t2 * 64 + c * 16 + rit;
            pa[i] = *(const uint4*)(ob + (((cc >> 5) * 256 + n) * 32) + (cc & 31));
        }
    }

    for (int ci = 0; ci < 2; ++ci) {               // chunks c = half*2 + ci
        const int c = half * 2 + ci;
        BAR_LDS();                                 // Al free
#pragma unroll
        for (int i = 0; i < 4; ++i) {
            int e = i * 2048 + tid * 8;
            *(uint4*)&Al[(e >> 7) * 136 + (e & 127)] = pa[i];
        }
        BAR_LDS();

        if (ci == 0) {                             // issue chunk c+1 loads now
            int c1 = c + 1;
#pragma unroll
            for (int i = 0; i < 4; ++i) {
                int e = i * 2048 + tid * 8;
                int lr2 = e >> 7, cc = e & 127;
                int t2 = lr2 >> 4, rit = lr2 & 15;
                int n = t2 * 64 + c1 * 16 + rit;
                pa[i] = *(const uint4*)(ob + (((cc >> 5) * 256 + n) * 32) + (cc & 31));
            }
        }

        f32x4 acc[4][2];
#pragma unroll
        for (int t2 = 0; t2 < 4; ++t2)
#pragma unroll
            for (int ntl = 0; ntl < 2; ++ntl)
                acc[t2][ntl] = (f32x4){0.f, 0.f, 0.f, 0.f};
#pragma unroll
        for (int kk = 0; kk < 4; ++kk) {
            bf16x8 a[4];
#pragma unroll
            for (int t2 = 0; t2 < 4; ++t2)
                a[t2] = *(const bf16x8*)&Al[(t2 * 16 + l15) * 136 + kk * 32 + lh * 8];
#pragma unroll
            for (int ntl = 0; ntl < 2; ++ntl) {
                bf16x8 bb = *(const bf16x8*)&Wl[((wv * 2 + ntl) * 16 + l15) * 136 + kk * 32 + lh * 8];
#pragma unroll
                for (int t2 = 0; t2 < 4; ++t2)
                    acc[t2][ntl] = MFMA16(a[t2], bb, acc[t2][ntl]);
            }
        }
        // bias + LIF over t2, store spikes (f32 0/1, nontemporal)
#pragma unroll
        for (int ntl = 0; ntl < 2; ++ntl) {
            int d = (wv * 2 + ntl) * 16 + l15;
#pragma unroll
            for (int reg = 0; reg < 4; ++reg) {
                int hw = c * 16 + lh * 4 + reg;
                float v = 0.f;
#pragma unroll
                for (int t2 = 0; t2 < 4; ++t2) {
                    float y = acc[t2][ntl][reg] + biasf[ntl];
                    v = v + (y - v) * 0.5f;
                    float s = (v >= 1.0f) ? 1.0f : 0.0f;
                    v = v * (1.0f - s);
                    __builtin_nontemporal_store(
                        s, out0 + t2 * 2097152 + b * 8192 + hw * 128 + d);
                }
            }
        }
    }
}

// ---------------------------------------------------------------------------
extern "C" void kernel_launch(void* const* d_in, const int* in_sizes, int n_in,
                              void* d_out, int out_size, void* d_ws, size_t ws_size,
                              hipStream_t stream)
{
    const float* x   = (const float*)d_in[0];
    const float* Wq  = (const float*)d_in[1];
    const float* Wk  = (const float*)d_in[2];
    const float* Wv  = (const float*)d_in[3];
    const float* tbl = (const float*)d_in[4];
    const float* Wp  = (const float*)d_in[5];
    const float* bp  = (const float*)d_in[6];

    float* out0 = (float*)d_out;                                // 8388608 f32
    float* attn = out0 + 8388608;                               // 67108864 f32

    unsigned short* o_ws = (unsigned short*)d_ws;               // 8388608 bf16
    unsigned int* qbits = (unsigned int*)(o_ws + 8388608);      // 262144 u32
    unsigned int* kbits = qbits + 262144;
    unsigned int* vbits = kbits + 262144;
    // total ws use: ~20 MB

    k_qkv_lif<<<dim3(256, 3), 256, 0, stream>>>(x, Wq, Wk, Wv,
                                                qbits, kbits, vbits);
    k_attn<<<1024, 256, 0, stream>>>(qbits, kbits, vbits, tbl, attn, o_ws);
    k_proj_lif<<<512, 256, 0, stream>>>(o_ws, Wp, bp, out0);

    // R10 PROBE: two extra idempotent k_attn launches.
    // dur - 353.5 = 2 x warm-cost(k_attn). See decision rule in header.
    k_attn<<<1024, 256, 0, stream>>>(qbits, kbits, vbits, tbl, attn, o_ws);
    k_attn<<<1024, 256, 0, stream>>>(qbits, kbits, vbits, tbl, attn, o_ws);
}

// Round 7
// 354.339 us; speedup vs baseline: 1.3253x; 1.3253x over previous
//
#include <hip/hip_runtime.h>
#include <hip/hip_bf16.h>

// ---------------------------------------------------------------------------
// Spiking Swin block: QKV(+LIF) -> binary attention (+rpb) -> PV -> proj(+LIF)
// I/O: float32. MFMA bf16 16x16x32 for GEMM work (exact for 0/1 spikes).
//
// Measurement ledger:
//  R3: timed window has ~245us harness poison fills (fixed); ours ~110us.
//  R5: LDS-only barriers (no vmcnt drain): NULL.
//  R7: rpb 268MB read stream -> 6.3KB LDS gather: NULL (L3 had hidden it).
//  R8 PROBE (2x pipeline): warm pipeline cost = 91us; floors ~60us.
//  R9: k_proj 2 blocks/CU + T14 prefetch x2: NULL.
//  R10 PROBE (2 extra k_attn): warm k_attn = 56.6us vs ~46us store floor
//     -> ~11us interior fat in k_attn; qkv/proj near floor; ~8-12us gaps.
//  R11 (this round): BARRIER-FREE k_attn. Each wave owns a 64-row band
//     (n = wv*64 + rt*16 + j), so the PV A-tile (16 rows) is wave-private
//     -> per-wave private attn LDS chunk, no workgroup barriers in the
//     main loop (only within-wave lgkmcnt). Waves free-run: store stream
//     stays continuous instead of lockstep-bursty. LDS 55.2KB -> 2
//     blocks/CU (occupancy halves; bet: issue-continuity > latency-hiding
//     since nontemporal stores are fire-and-forget).
// ---------------------------------------------------------------------------

typedef __attribute__((ext_vector_type(8))) short bf16x8;   // 8 bf16 = 4 VGPRs
typedef __attribute__((ext_vector_type(4))) float f32x4;

#define MFMA16(a, b, c) __builtin_amdgcn_mfma_f32_16x16x32_bf16((a), (b), (c), 0, 0, 0)

// LDS-only barrier: wait own LDS ops, then rendezvous. Does NOT drain vmcnt.
#define BAR_LDS()                                                \
    do {                                                         \
        asm volatile("s_waitcnt lgkmcnt(0)" ::: "memory");       \
        __builtin_amdgcn_s_barrier();                            \
    } while (0)

// Within-wave LDS fence: own ds_writes complete before following ds_reads.
// sched_barrier stops the scheduler hoisting dependent ops above it (rule 18).
#define FENCE_LDS_WAVE()                                         \
    do {                                                         \
        asm volatile("s_waitcnt lgkmcnt(0)" ::: "memory");       \
        __builtin_amdgcn_sched_barrier(0);                       \
    } while (0)

__device__ __forceinline__ unsigned short f2bf(float f) {
    union { __hip_bfloat16 h; unsigned short u; } cv;
    cv.h = __float2bfloat16(f);                      // RNE
    return cv.u;
}

// Convert 8 f32 (two float4 regs) -> 8 bf16, 16B store to LDS.
__device__ __forceinline__ void cvt8_store_reg(unsigned short* dst, float4 f0, float4 f1) {
    unsigned short h[8];
    h[0] = f2bf(f0.x); h[1] = f2bf(f0.y); h[2] = f2bf(f0.z); h[3] = f2bf(f0.w);
    h[4] = f2bf(f1.x); h[5] = f2bf(f1.y); h[6] = f2bf(f1.z); h[7] = f2bf(f1.w);
    *(uint4*)dst = *(const uint4*)h;
}

__device__ __forceinline__ void cvt8_store(unsigned short* dst, const float* src) {
    float4 f0 = *(const float4*)(src);
    float4 f1 = *(const float4*)(src + 4);
    cvt8_store_reg(dst, f0, f1);
}

// ---------------------------------------------------------------------------
// Kernel A: blockIdx.y in {0,1,2}: per-weight GEMM X@W^T (MFMA) + LIF over t,
// bit-packed spike output. x tile for t+1 register-prefetched (T14).
// ---------------------------------------------------------------------------
__global__ __launch_bounds__(256) void k_qkv_lif(
    const float* __restrict__ x,
    const float* __restrict__ Wq,
    const float* __restrict__ Wk,
    const float* __restrict__ Wv,
    unsigned int* __restrict__ qbits,
    unsigned int* __restrict__ kbits,
    unsigned int* __restrict__ vbits)
{
    __shared__ unsigned short Wl[128 * 136];   // W rows d (N) x cols c (K), pad +8
    __shared__ unsigned short Xl[64 * 136];    // X tile / spike tile (reused)

    const int tid = threadIdx.x;
    const int wv = tid >> 6, lane = tid & 63;
    const int l15 = lane & 15, lh = lane >> 4;
    const int wsel = blockIdx.y;
    const float* W = (wsel == 0) ? Wq : (wsel == 1) ? Wk : Wv;
    unsigned int* bits = (wsel == 0) ? qbits : (wsel == 1) ? kbits : vbits;
    const int B = blockIdx.x;

    {   // stage W (128x128 f32 -> bf16)
#pragma unroll
        for (int i = 0; i < 8; ++i) {
            int e = i * 2048 + tid * 8;
            cvt8_store(&Wl[(e >> 7) * 136 + (e & 127)], W + e);
        }
    }

    // prefetch x(t=0): 32 floats/thread in regs (e = r*128+cc flat)
    float4 px[8];
    {
        const float* xg = x + B * 8192;
#pragma unroll
        for (int i = 0; i < 4; ++i) {
            int e = i * 2048 + tid * 8;
            px[2 * i]     = *(const float4*)(xg + e);
            px[2 * i + 1] = *(const float4*)(xg + e + 4);
        }
    }

    f32x4 vst[8];                                   // LIF membrane, persists over t
#pragma unroll
    for (int nt = 0; nt < 8; ++nt) vst[nt] = (f32x4){0.f, 0.f, 0.f, 0.f};

    for (int t = 0; t < 4; ++t) {
        BAR_LDS();                                  // Xl free (pack reads done)
#pragma unroll
        for (int i = 0; i < 4; ++i) {               // regs -> bf16 -> Xl
            int e = i * 2048 + tid * 8;
            cvt8_store_reg(&Xl[(e >> 7) * 136 + (e & 127)], px[2 * i], px[2 * i + 1]);
        }
        BAR_LDS();

        if (t < 3) {                                // issue t+1 loads NOW;
            const float* xg = x + (t + 1) * 2097152 + B * 8192;  // fly under MFMA
#pragma unroll
            for (int i = 0; i < 4; ++i) {
                int e = i * 2048 + tid * 8;
                px[2 * i]     = *(const float4*)(xg + e);
                px[2 * i + 1] = *(const float4*)(xg + e + 4);
            }
        }

        f32x4 acc[8];
#pragma unroll
        for (int nt = 0; nt < 8; ++nt) acc[nt] = (f32x4){0.f, 0.f, 0.f, 0.f};
#pragma unroll
        for (int kk = 0; kk < 4; ++kk) {
            bf16x8 a = *(const bf16x8*)&Xl[(wv * 16 + l15) * 136 + kk * 32 + lh * 8];
#pragma unroll
            for (int nt = 0; nt < 8; ++nt) {
                bf16x8 b = *(const bf16x8*)&Wl[(nt * 16 + l15) * 136 + kk * 32 + lh * 8];
                acc[nt] = MFMA16(a, b, acc[nt]);
            }
        }
        // LIF: v += (y-v)/2; s=(v>=1); v*=(1-s); spike shorts -> Xl
        unsigned short sp[8][4];
#pragma unroll
        for (int nt = 0; nt < 8; ++nt) {
#pragma unroll
            for (int reg = 0; reg < 4; ++reg) {
                float y = acc[nt][reg];
                float v = vst[nt][reg];
                v = v + (y - v) * 0.5f;
                float s = (v >= 1.0f) ? 1.0f : 0.0f;
                vst[nt][reg] = v * (1.0f - s);
                sp[nt][reg] = (s != 0.0f) ? (unsigned short)1 : (unsigned short)0;
            }
        }
        BAR_LDS();                                  // all MFMA reads of Xl done
#pragma unroll
        for (int nt = 0; nt < 8; ++nt)
#pragma unroll
            for (int reg = 0; reg < 4; ++reg)
                Xl[(wv * 16 + lh * 4 + reg) * 136 + nt * 16 + l15] = sp[nt][reg];
        BAR_LDS();
        // pack: thread u owns n=u: row hw=u>>2, cols (u&3)*32 .. +31 -> 32 bits
        {
            const unsigned short* rowp = &Xl[(tid >> 2) * 136 + (tid & 3) * 32];
            unsigned int mask = 0;
#pragma unroll
            for (int j8 = 0; j8 < 4; ++j8) {
                uint4 u = *(const uint4*)(rowp + j8 * 8);
                int base = j8 * 8;
                if (u.x & 0xFFFFu) mask |= 1u << (base + 0);
                if (u.x >> 16)     mask |= 1u << (base + 1);
                if (u.y & 0xFFFFu) mask |= 1u << (base + 2);
                if (u.y >> 16)     mask |= 1u << (base + 3);
                if (u.z & 0xFFFFu) mask |= 1u << (base + 4);
                if (u.z >> 16)     mask |= 1u << (base + 5);
                if (u.w & 0xFFFFu) mask |= 1u << (base + 6);
                if (u.w >> 16)     mask |= 1u << (base + 7);
            }
            bits[(t * 256 + B) * 256 + tid] = mask;  // coalesced 1KB
        }
    }
}

// ---------------------------------------------------------------------------
// Kernel B (R11): barrier-free main loop. One block per group g=(b,head).
// Each wave owns rows n = wv*64 .. wv*64+63 (4 subtiles of 16 rows).
// Per subtile: produce 16 attn rows (popc*SC + LDS-rpb-gather, nontemporal
// f32x4 store, bf16 copy into WAVE-PRIVATE attn chunk) -> within-wave
// lgkmcnt fence -> 16 MFMA (both d-halves) -> o store. No s_barrier after
// the prologue; waves free-run so the CU store pipe never drains in
// lockstep. attnW pad +4 (260): A-read 4-way banks (vs 8-way at +8).
// LDS: vT 16.9K + attnW 4x8.3K + tblL 6.3K = 55.2 KB -> 2 blocks/CU.
// ---------------------------------------------------------------------------
__global__ __launch_bounds__(256) void k_attn(
    const unsigned int* __restrict__ qbits,
    const unsigned int* __restrict__ kbits,
    const unsigned int* __restrict__ vbits,
    const float* __restrict__ tbl,
    float* __restrict__ attn_out,
    unsigned short* __restrict__ o_ws)
{
    __shared__ unsigned short vT[32 * 264];        // v transposed: [d][m], pad +8
    __shared__ unsigned short attnW[4][16 * 260];  // per-wave attn chunk, pad +4
    __shared__ float tblL[1575];                   // per-head rpb base (7*15*15)

    const int tid = threadIdx.x;
    const int wv = tid >> 6, lane = tid & 63;
    const int l15 = lane & 15, lh = lane >> 4;
    const int g = blockIdx.x, hh = g & 3;

    // stage per-head rpb table: tblL[ri] = tbl[ri*4 + hh]
    for (int i = tid; i < 1575; i += 256)
        tblL[i] = tbl[i * 4 + hh];

    uint4 km = *(const uint4*)&kbits[g * 256 + lane * 4];
    {   // v bits -> bf16 vT[d][m]
        unsigned int vb = vbits[g * 256 + tid];
#pragma unroll
        for (int d = 0; d < 32; ++d)
            vT[d * 264 + tid] = ((vb >> d) & 1u) ? (unsigned short)0x3F80
                                                 : (unsigned short)0;
    }

    // per-lane dm for the 4 owned columns m = m0..m0+3 (ri = base(n) - dm)
    const int m0 = lane * 4;
    int dm[4];
#pragma unroll
    for (int i = 0; i < 4; ++i) {
        int m = m0 + i;
        dm[i] = (m >> 6) * 225 + ((m >> 3) & 7) * 15 + (m & 7);
    }

    BAR_LDS();                                 // vT + tblL ready (only barrier)

    const float SC = 0.17677669529663687f;     // 32^-0.5
    float* attn_b = attn_out + (size_t)g * 65536;
    unsigned short* ob = o_ws + g * 8192;
    const int nb = __builtin_amdgcn_readfirstlane(wv * 64);  // wave row band
    unsigned short* aw = &attnW[wv][0];

    for (int rt = 0; rt < 4; ++rt) {           // 16-row subtiles, wave-private
#pragma unroll
        for (int j = 0; j < 16; ++j) {
            int n = nb + rt * 16 + j;                        // wave-uniform
            unsigned int qn = qbits[g * 256 + n];            // s_load (uniform)
            int zn = n >> 6, yn = (n >> 3) & 7, xn = n & 7;
            int basei = zn * 225 + yn * 15 + xn + 787;       // scalar
            f32x4 av;
            av.x = (float)__popc(qn & km.x) * SC + tblL[basei - dm[0]];
            av.y = (float)__popc(qn & km.y) * SC + tblL[basei - dm[1]];
            av.z = (float)__popc(qn & km.z) * SC + tblL[basei - dm[2]];
            av.w = (float)__popc(qn & km.w) * SC + tblL[basei - dm[3]];
            __builtin_nontemporal_store(av, (f32x4*)(attn_b + n * 256 + m0));
            unsigned int p0 = (unsigned int)f2bf(av.x) | ((unsigned int)f2bf(av.y) << 16);
            unsigned int p1 = (unsigned int)f2bf(av.z) | ((unsigned int)f2bf(av.w) << 16);
            uint2 pk; pk.x = p0; pk.y = p1;
            *(uint2*)&aw[j * 260 + m0] = pk;
        }
        FENCE_LDS_WAVE();                      // own attnW writes landed

        // o(16x32) = aw(16x256) @ v(256x32); both 16-d halves in one wave
        f32x4 oc0 = (f32x4){0.f, 0.f, 0.f, 0.f};
        f32x4 oc1 = (f32x4){0.f, 0.f, 0.f, 0.f};
#pragma unroll
        for (int kk = 0; kk < 8; ++kk) {
            bf16x8 a  = *(const bf16x8*)&aw[l15 * 260 + kk * 32 + lh * 8];
            bf16x8 b0 = *(const bf16x8*)&vT[l15 * 264 + kk * 32 + lh * 8];
            bf16x8 b1 = *(const bf16x8*)&vT[(16 + l15) * 264 + kk * 32 + lh * 8];
            oc0 = MFMA16(a, b0, oc0);
            oc1 = MFMA16(a, b1, oc1);
        }
#pragma unroll
        for (int reg = 0; reg < 4; ++reg) {
            int n = nb + rt * 16 + lh * 4 + reg;
            ob[n * 32 + l15]      = f2bf(oc0[reg]);
            ob[n * 32 + 16 + l15] = f2bf(oc1[reg]);
        }
        // next rt overwrites aw: per-wave DS ops execute in order -> safe.
    }
}

// ---------------------------------------------------------------------------
// Kernel C: gather o across heads -> A(256x128); Y = A@Wp^T + bias; LIF over
// t2. Grid 512 = (b, half); 2 blocks/CU, 8 waves; T14 chunk prefetch.
// ---------------------------------------------------------------------------
__global__ __launch_bounds__(256) void k_proj_lif(
    const unsigned short* __restrict__ o_ws,
    const float* __restrict__ Wp,
    const float* __restrict__ bp,
    float* __restrict__ out0)
{
    __shared__ unsigned short Wl[128 * 136];
    __shared__ unsigned short Al[64 * 136];

    const int tid = threadIdx.x;
    const int wv = tid >> 6, lane = tid & 63;
    const int l15 = lane & 15, lh = lane >> 4;
    const int b = blockIdx.x >> 1, half = blockIdx.x & 1;

    {   // stage Wproj (f32 -> bf16)
#pragma unroll
        for (int i = 0; i < 8; ++i) {
            int e = i * 2048 + tid * 8;
            cvt8_store(&Wl[(e >> 7) * 136 + (e & 127)], Wp + e);
        }
    }

    float biasf[2];
#pragma unroll
    for (int ntl = 0; ntl < 2; ++ntl)
        biasf[ntl] = bp[(wv * 2 + ntl) * 16 + l15];

    const unsigned short* ob = o_ws + b * 32768;   // o[b][head][n][hd] bf16

    // prefetch chunk c0 = half*2: Al rows lr2 = t2*16+rit, cols cc = head*32+hd
    uint4 pa[4];
    {
        int c = half * 2;
#pragma unroll
        for (int i = 0; i < 4; ++i) {
            int e = i * 2048 + tid * 8;
            int lr2 = e >> 7, cc = e & 127;
            int t2 = lr2 >> 4, rit = lr2 & 15;
            int n = t2 * 64 + c * 16 + rit;
            pa[i] = *(const uint4*)(ob + (((cc >> 5) * 256 + n) * 32) + (cc & 31));
        }
    }

    for (int ci = 0; ci < 2; ++ci) {               // chunks c = half*2 + ci
        const int c = half * 2 + ci;
        BAR_LDS();                                 // Al free
#pragma unroll
        for (int i = 0; i < 4; ++i) {
            int e = i * 2048 + tid * 8;
            *(uint4*)&Al[(e >> 7) * 136 + (e & 127)] = pa[i];
        }
        BAR_LDS();

        if (ci == 0) {                             // issue chunk c+1 loads now
            int c1 = c + 1;
#pragma unroll
            for (int i = 0; i < 4; ++i) {
                int e = i * 2048 + tid * 8;
                int lr2 = e >> 7, cc = e & 127;
                int t2 = lr2 >> 4, rit = lr2 & 15;
                int n = t2 * 64 + c1 * 16 + rit;
                pa[i] = *(const uint4*)(ob + (((cc >> 5) * 256 + n) * 32) + (cc & 31));
            }
        }

        f32x4 acc[4][2];
#pragma unroll
        for (int t2 = 0; t2 < 4; ++t2)
#pragma unroll
            for (int ntl = 0; ntl < 2; ++ntl)
                acc[t2][ntl] = (f32x4){0.f, 0.f, 0.f, 0.f};
#pragma unroll
        for (int kk = 0; kk < 4; ++kk) {
            bf16x8 a[4];
#pragma unroll
            for (int t2 = 0; t2 < 4; ++t2)
                a[t2] = *(const bf16x8*)&Al[(t2 * 16 + l15) * 136 + kk * 32 + lh * 8];
#pragma unroll
            for (int ntl = 0; ntl < 2; ++ntl) {
                bf16x8 bb = *(const bf16x8*)&Wl[((wv * 2 + ntl) * 16 + l15) * 136 + kk * 32 + lh * 8];
#pragma unroll
                for (int t2 = 0; t2 < 4; ++t2)
                    acc[t2][ntl] = MFMA16(a[t2], bb, acc[t2][ntl]);
            }
        }
        // bias + LIF over t2, store spikes (f32 0/1, nontemporal)
#pragma unroll
        for (int ntl = 0; ntl < 2; ++ntl) {
            int d = (wv * 2 + ntl) * 16 + l15;
#pragma unroll
            for (int reg = 0; reg < 4; ++reg) {
                int hw = c * 16 + lh * 4 + reg;
                float v = 0.f;
#pragma unroll
                for (int t2 = 0; t2 < 4; ++t2) {
                    float y = acc[t2][ntl][reg] + biasf[ntl];
                    v = v + (y - v) * 0.5f;
                    float s = (v >= 1.0f) ? 1.0f : 0.0f;
                    v = v * (1.0f - s);
                    __builtin_nontemporal_store(
                        s, out0 + t2 * 2097152 + b * 8192 + hw * 128 + d);
                }
            }
        }
    }
}

// ---------------------------------------------------------------------------
extern "C" void kernel_launch(void* const* d_in, const int* in_sizes, int n_in,
                              void* d_out, int out_size, void* d_ws, size_t ws_size,
                              hipStream_t stream)
{
    const float* x   = (const float*)d_in[0];
    const float* Wq  = (const float*)d_in[1];
    const float* Wk  = (const float*)d_in[2];
    const float* Wv  = (const float*)d_in[3];
    const float* tbl = (const float*)d_in[4];
    const float* Wp  = (const float*)d_in[5];
    const float* bp  = (const float*)d_in[6];

    float* out0 = (float*)d_out;                                // 8388608 f32
    float* attn = out0 + 8388608;                               // 67108864 f32

    unsigned short* o_ws = (unsigned short*)d_ws;               // 8388608 bf16
    unsigned int* qbits = (unsigned int*)(o_ws + 8388608);      // 262144 u32
    unsigned int* kbits = qbits + 262144;
    unsigned int* vbits = kbits + 262144;
    // total ws use: ~20 MB

    k_qkv_lif<<<dim3(256, 3), 256, 0, stream>>>(x, Wq, Wk, Wv,
                                                qbits, kbits, vbits);
    k_attn<<<1024, 256, 0, stream>>>(qbits, kbits, vbits, tbl, attn, o_ws);
    k_proj_lif<<<512, 256, 0, stream>>>(o_ws, Wp, bp, out0);
}